// Round 4
// baseline (245.453 us; speedup 1.0000x reference)
//
#include <hip/hip_runtime.h>
#include <math.h>

#define GN 2048
#define GD_IN 128
#define GD_OUT 64

typedef float f4 __attribute__((ext_vector_type(4)));
typedef int   i4 __attribute__((ext_vector_type(4)));

// Kernel 1: h = X @ W^T  [N, D_OUT]; s_i = h @ a[:64]; s_j = h @ a[64:]
__global__ __launch_bounds__(64) void gat_h_kernel(
    const float* __restrict__ x,   // [N, 128]
    const float* __restrict__ W,   // [64, 128]
    const float* __restrict__ a,   // [128]
    float* __restrict__ h,         // [N, 64]
    float* __restrict__ s_i,       // [N]
    float* __restrict__ s_j) {     // [N]
    __shared__ float wl[GD_OUT * (GD_IN + 1)];  // +1 pad -> conflict-free
    __shared__ float xl[GD_IN];
    const int i = blockIdx.x;
    const int t = threadIdx.x;  // 0..63

    for (int idx = t; idx < GD_OUT * GD_IN; idx += 64) {
        int o = idx >> 7, k = idx & 127;
        wl[o * (GD_IN + 1) + k] = W[idx];
    }
    xl[t]      = x[i * GD_IN + t];
    xl[t + 64] = x[i * GD_IN + t + 64];
    __syncthreads();

    float acc = 0.f;
    const float* wr = &wl[t * (GD_IN + 1)];
    #pragma unroll
    for (int k = 0; k < GD_IN; ++k) acc = fmaf(xl[k], wr[k], acc);
    h[i * GD_OUT + t] = acc;

    float p1 = acc * a[t];
    float p2 = acc * a[GD_OUT + t];
    #pragma unroll
    for (int off = 32; off; off >>= 1) {
        p1 += __shfl_down(p1, off);
        p2 += __shfl_down(p2, off);
    }
    if (t == 0) { s_i[i] = p1; s_j[i] = p2; }
}

// Kernel 2 (fused): one block per row i. Vectorized prologue (int4 mask,
// float4 s_j, b128 LDS) -> softmax -> prescaled alpha in LDS -> write phase
// rotated per block to decorrelate HBM channel access across blocks.
__global__ __launch_bounds__(256) void gat_msg_kernel(
    const int* __restrict__ mask,  // [N, N] int32 (0/1)
    const float* __restrict__ h,   // [N, 64]
    const float* __restrict__ s_i, // [N]
    const float* __restrict__ s_j, // [N]
    float* __restrict__ out) {     // [N, N, 64]
    __shared__ f4 sc4[GN / 4];     // scores -> exp -> alpha (as float4)
    __shared__ float red[4];
    const int i = blockIdx.x;
    const int t = threadIdx.x;  // 0..255
    const float si = s_i[i];

    const i4* __restrict__ mask4 = reinterpret_cast<const i4*>(mask) + (size_t)i * (GN / 4);
    const f4* __restrict__ sj4 = reinterpret_cast<const f4*>(s_j);
    float* sc = reinterpret_cast<float*>(sc4);

    // Pass 1: masked leaky-relu scores + local max. Thread owns j = 4q..4q+3.
    float lmax = -INFINITY;
    #pragma unroll
    for (int q = t; q < GN / 4; q += 256) {
        i4 m = mask4[q];
        f4 sj = sj4[q];
        f4 s;
        #pragma unroll
        for (int k = 0; k < 4; ++k) {
            float z = si + sj[k];
            float v = z > 0.f ? z : 0.01f * z;
            s[k] = m[k] ? v : -INFINITY;
            lmax = fmaxf(lmax, s[k]);
        }
        sc4[q] = s;
    }
    #pragma unroll
    for (int off = 32; off; off >>= 1) lmax = fmaxf(lmax, __shfl_down(lmax, off));
    if ((t & 63) == 0) red[t >> 6] = lmax;
    __syncthreads();
    float rmax = fmaxf(fmaxf(red[0], red[1]), fmaxf(red[2], red[3]));
    if (rmax == -INFINITY) rmax = 0.f;  // all-invalid row -> alpha row = 0

    // Pass 2: exp + local sum
    float lsum = 0.f;
    #pragma unroll
    for (int q = t; q < GN / 4; q += 256) {
        f4 s = sc4[q];
        #pragma unroll
        for (int k = 0; k < 4; ++k) {
            s[k] = __expf(s[k] - rmax);   // exp(-inf) == 0 for unmasked
            lsum += s[k];
        }
        sc4[q] = s;
    }
    #pragma unroll
    for (int off = 32; off; off >>= 1) lsum += __shfl_down(lsum, off);
    __syncthreads();
    if ((t & 63) == 0) red[t >> 6] = lsum;
    __syncthreads();
    const float ssum = red[0] + red[1] + red[2] + red[3];
    const float inv = ssum > 0.f ? 1.f / ssum : 0.f;

    // Pass 3: prescale alpha in place
    #pragma unroll
    for (int q = t; q < GN / 4; q += 256) sc4[q] *= inv;
    __syncthreads();

    // Write phase: 16 j's x 16 float4-lanes per iteration, rotated start per
    // block (i*16 j's = i*4KB) to decorrelate HBM channels across blocks.
    const f4* __restrict__ h4 = reinterpret_cast<const f4*>(h);
    f4* __restrict__ out4 = reinterpret_cast<f4*>(out) + (size_t)i * GN * (GD_OUT / 4);
    const int jl = t >> 4;   // 0..15
    const int o4 = t & 15;   // 0..15
    const int rot = (i << 4) & (GN - 1);
    #pragma unroll 4
    for (int jb = 0; jb < GN; jb += 16) {
        int j = ((jb + rot) & (GN - 1)) + jl;
        float al = sc[j];                // LDS broadcast (16 lanes share j)
        f4 hv = h4[j * (GD_OUT / 4) + o4];
        out4[(size_t)j * (GD_OUT / 4) + o4] = hv * al;
    }
}

extern "C" void kernel_launch(void* const* d_in, const int* in_sizes, int n_in,
                              void* d_out, int out_size, void* d_ws, size_t ws_size,
                              hipStream_t stream) {
    const float* x    = (const float*)d_in[0];   // [2048, 128]
    const int*   mask = (const int*)d_in[1];     // [2048, 2048]
    const float* W    = (const float*)d_in[2];   // [64, 128]
    const float* a    = (const float*)d_in[3];   // [128]
    float* out = (float*)d_out;                  // [2048, 2048, 64]

    float* ws  = (float*)d_ws;
    float* h   = ws;                 // 2048*64 floats
    float* s_i = ws + GN * GD_OUT;   // 2048 floats
    float* s_j = s_i + GN;           // 2048 floats

    gat_h_kernel<<<GN, 64, 0, stream>>>(x, W, a, h, s_i, s_j);
    gat_msg_kernel<<<GN, 256, 0, stream>>>(mask, h, s_i, s_j, out);
}

// Round 5
// 217.518 us; speedup vs baseline: 1.1284x; 1.1284x over previous
//
#include <hip/hip_runtime.h>
#include <math.h>

#define GN 2048
#define GD_IN 128
#define GD_OUT 64

typedef float f4 __attribute__((ext_vector_type(4)));
typedef int   i4 __attribute__((ext_vector_type(4)));

// Kernel 1: h = X @ W^T  [N, D_OUT]; s_i = h @ a[:64]; s_j = h @ a[64:]
__global__ __launch_bounds__(64) void gat_h_kernel(
    const float* __restrict__ x,   // [N, 128]
    const float* __restrict__ W,   // [64, 128]
    const float* __restrict__ a,   // [128]
    float* __restrict__ h,         // [N, 64]
    float* __restrict__ s_i,       // [N]
    float* __restrict__ s_j) {     // [N]
    __shared__ float wl[GD_OUT * (GD_IN + 1)];
    __shared__ float xl[GD_IN];
    const int i = blockIdx.x;
    const int t = threadIdx.x;  // 0..63

    for (int idx = t; idx < GD_OUT * GD_IN; idx += 64) {
        int o = idx >> 7, k = idx & 127;
        wl[o * (GD_IN + 1) + k] = W[idx];
    }
    xl[t]      = x[i * GD_IN + t];
    xl[t + 64] = x[i * GD_IN + t + 64];
    __syncthreads();

    float acc = 0.f;
    const float* wr = &wl[t * (GD_IN + 1)];
    #pragma unroll
    for (int k = 0; k < GD_IN; ++k) acc = fmaf(xl[k], wr[k], acc);
    h[i * GD_OUT + t] = acc;

    float p1 = acc * a[t];
    float p2 = acc * a[GD_OUT + t];
    #pragma unroll
    for (int off = 32; off; off >>= 1) {
        p1 += __shfl_down(p1, off);
        p2 += __shfl_down(p2, off);
    }
    if (t == 0) { s_i[i] = p1; s_j[i] = p2; }
}

// Kernel 2: one block = 4 rows. Wave w owns row i0+w: wave-local softmax
// (scores in registers), prescaled alpha -> LDS. Write phase: thread owns
// fixed (j, o4); loads h4[j] ONCE, stores into 4 rows (4x h-load reuse).
__global__ __launch_bounds__(256) void gat_msg_kernel(
    const int* __restrict__ mask,  // [N, N] int32 (0/1)
    const float* __restrict__ h,   // [N, 64]
    const float* __restrict__ s_i, // [N]
    const float* __restrict__ s_j, // [N]
    float* __restrict__ out) {     // [N, N, 64]
    __shared__ f4 alph4[4][GN / 4];  // prescaled alpha, 32 KB
    const int t = threadIdx.x;       // 0..255
    const int w = t >> 6;            // wave 0..3
    const int lane = t & 63;
    const int i0 = blockIdx.x << 2;
    const int row = i0 + w;

    // ---- Prologue: wave-local softmax for row `row`, scores in registers
    const float si = s_i[row];
    const i4* __restrict__ mask4 = reinterpret_cast<const i4*>(mask) + (size_t)row * (GN / 4);
    const f4* __restrict__ sj4 = reinterpret_cast<const f4*>(s_j);

    f4 s[8];
    float lmax = -INFINITY;
    #pragma unroll
    for (int k = 0; k < 8; ++k) {
        int q = k * 64 + lane;
        i4 m = mask4[q];
        f4 sj = sj4[q];
        #pragma unroll
        for (int c = 0; c < 4; ++c) {
            float z = si + sj[c];
            float v = z > 0.f ? z : 0.01f * z;
            s[k][c] = m[c] ? v : -INFINITY;
            lmax = fmaxf(lmax, s[k][c]);
        }
    }
    #pragma unroll
    for (int off = 32; off; off >>= 1) lmax = fmaxf(lmax, __shfl_xor(lmax, off));
    float rmax = lmax == -INFINITY ? 0.f : lmax;  // all-invalid row -> alpha 0

    float lsum = 0.f;
    #pragma unroll
    for (int k = 0; k < 8; ++k) {
        #pragma unroll
        for (int c = 0; c < 4; ++c) {
            s[k][c] = __expf(s[k][c] - rmax);  // exp(-inf) = 0 for unmasked
            lsum += s[k][c];
        }
    }
    #pragma unroll
    for (int off = 32; off; off >>= 1) lsum += __shfl_xor(lsum, off);
    const float inv = lsum > 0.f ? 1.f / lsum : 0.f;

    #pragma unroll
    for (int k = 0; k < 8; ++k) alph4[w][k * 64 + lane] = s[k] * inv;
    __syncthreads();

    // ---- Write phase: thread owns (jl, o4); h4[j] loaded once per 4 rows.
    const float* alpha = reinterpret_cast<const float*>(alph4);  // [4][GN]
    const f4* __restrict__ h4 = reinterpret_cast<const f4*>(h);
    f4* __restrict__ out4 = reinterpret_cast<f4*>(out);
    const int jl = t >> 4;   // 0..15
    const int o4 = t & 15;   // 0..15
    #pragma unroll 2
    for (int jb = 0; jb < GN; jb += 16) {
        const int j = jb + jl;
        const f4 hv = h4[j * (GD_OUT / 4) + o4];
        #pragma unroll
        for (int ii = 0; ii < 4; ++ii) {
            float al = alpha[ii * GN + j];   // LDS broadcast (16 lanes share)
            out4[((size_t)(i0 + ii) * GN + j) * (GD_OUT / 4) + o4] = hv * al;
        }
    }
}

extern "C" void kernel_launch(void* const* d_in, const int* in_sizes, int n_in,
                              void* d_out, int out_size, void* d_ws, size_t ws_size,
                              hipStream_t stream) {
    const float* x    = (const float*)d_in[0];   // [2048, 128]
    const int*   mask = (const int*)d_in[1];     // [2048, 2048]
    const float* W    = (const float*)d_in[2];   // [64, 128]
    const float* a    = (const float*)d_in[3];   // [128]
    float* out = (float*)d_out;                  // [2048, 2048, 64]

    float* ws  = (float*)d_ws;
    float* h   = ws;                 // 2048*64 floats
    float* s_i = ws + GN * GD_OUT;   // 2048 floats
    float* s_j = s_i + GN;           // 2048 floats

    gat_h_kernel<<<GN, 64, 0, stream>>>(x, W, a, h, s_i, s_j);
    gat_msg_kernel<<<GN / 4, 256, 0, stream>>>(mask, h, s_i, s_j, out);
}